// Round 3
// baseline (294.951 us; speedup 1.0000x reference)
//
#include <hip/hip_runtime.h>
#include <hip/hip_bf16.h>

#define NB 1024
#define NTOBS 100
#define NT 120
#define ND 256
#define LAT_BSTRIDE (NTOBS * ND)   // 25600
#define OUT_BSTRIDE (NT * ND)      // 30720

#define SEQ_NBLK 64                       // 16 rows per seq block
#define PAR_ROWS 64                       // rows per parallel block
#define PAR_BLKS (98 * (NB / PAR_ROWS))   // 98 evals * 16 = 1568

typedef __attribute__((ext_vector_type(8))) short bf16x8;
typedef __attribute__((ext_vector_type(4))) float f32x4;
typedef __attribute__((ext_vector_type(4))) short short4v;

__device__ __forceinline__ short f2bf(float f) {
    unsigned u = __float_as_uint(f);
    unsigned r = (u + 0x7fffu + ((u >> 16) & 1u)) >> 16;
    return (short)(r & 0xffffu);
}

__device__ __forceinline__ float fast_tanh(float x) {
    float e = __expf(2.0f * x);
    return 1.0f - 2.0f / (e + 1.0f);
}

// ---------------------------------------------------------------------------
// prep: Wt[m][n*256+k] = bf16(W[k][n]); plus copy steps 0 and 2 (dt==0 quirk)
// ---------------------------------------------------------------------------
__global__ void prep_kernel(const float* __restrict__ W1,
                            const float* __restrict__ W2,
                            const float* __restrict__ W3,
                            const float* __restrict__ lat,
                            short* __restrict__ wt,
                            float* __restrict__ out)
{
    int tid = blockIdx.x * blockDim.x + threadIdx.x;
    int nth = gridDim.x * blockDim.x;
    for (int i = tid; i < 256 * 256; i += nth) {
        int n = i >> 8, k = i & 255;
        wt[i]             = f2bf(W1[k * 256 + n]);
        wt[i + 65536]     = f2bf(W2[k * 256 + n]);
        wt[i + 2 * 65536] = f2bf(W3[k * 256 + n]);
    }
    for (int i = tid; i < NB * ND; i += nth) {
        int b = i >> 8, c = i & 255;
        out[(size_t)b * OUT_BSTRIDE + 0 * ND + c] = lat[(size_t)b * LAT_BSTRIDE + 0 * ND + c];
        out[(size_t)b * OUT_BSTRIDE + 2 * ND + c] = lat[(size_t)b * LAT_BSTRIDE + 1 * ND + c];
    }
}

// ---------------------------------------------------------------------------
// Parallel-path layer: acc[rt][ct] += A(LDS bf16 swizzled, 64 rows) @ Wt(L2)
// 8 waves = 8 col-groups of 32 cols (no row duplication).
// MFMA 16x16x32 bf16: A[l16][lgr*8+j], B[k0+j][l16], D row=4*lgr+j col=l16
// ---------------------------------------------------------------------------
__device__ __forceinline__ void par_layer(f32x4 (&acc)[4][2],
    const char* __restrict__ srcbuf, const short* __restrict__ wtl,
    int cg, int l16, int lgr)
{
#pragma unroll
    for (int rt = 0; rt < 4; rt++)
#pragma unroll
        for (int ct = 0; ct < 2; ct++)
            acc[rt][ct] = (f32x4){0.f, 0.f, 0.f, 0.f};
#pragma unroll
    for (int kk = 0; kk < 8; kk++) {
        const int k0 = kk * 32 + lgr * 8;
        bf16x8 a[4], b[2];
#pragma unroll
        for (int rt = 0; rt < 4; rt++) {
            const int r = rt * 16 + l16;
            a[rt] = *(const bf16x8*)(srcbuf + ((r * 512 + k0 * 2) ^ ((r & 7) << 4)));
        }
#pragma unroll
        for (int ct = 0; ct < 2; ct++) {
            const int col = cg * 32 + ct * 16 + l16;
            b[ct] = *(const bf16x8*)(wtl + col * 256 + k0);
        }
#pragma unroll
        for (int rt = 0; rt < 4; rt++)
#pragma unroll
            for (int ct = 0; ct < 2; ct++)
                acc[rt][ct] = __builtin_amdgcn_mfma_f32_16x16x32_bf16(a[rt], b[ct], acc[rt][ct], 0, 0, 0);
    }
}

__device__ __forceinline__ void par_store_h(char* __restrict__ dst,
    const f32x4 (&acc)[4][2], const float bc[2], int cg, int l16, int lgr)
{
#pragma unroll
    for (int rt = 0; rt < 4; rt++)
#pragma unroll
        for (int ct = 0; ct < 2; ct++) {
            const int c = cg * 32 + ct * 16 + l16;
#pragma unroll
            for (int j = 0; j < 4; j++) {
                const int r = rt * 16 + lgr * 4 + j;
                const int off = (r * 512 + c * 2) ^ ((r & 7) << 4);
                *(short*)(dst + off) = f2bf(fast_tanh(acc[rt][ct][j] + bc[ct]));
            }
        }
}

// ---------------------------------------------------------------------------
// Fused main kernel, 512 threads (8 waves), <=128 regs, 64KB LDS -> 2 blk/CU.
//  blocks [0,64):     sequential chains k=100..119, 16 rows each
//  blocks [64,1632):  parallel f-evals, 64 rows each
// ---------------------------------------------------------------------------
__global__ __launch_bounds__(512, 4) void ode_main(
    const float* __restrict__ lat, const float* __restrict__ ts,
    const short* __restrict__ wt,
    const float* __restrict__ b1, const float* __restrict__ b2,
    const float* __restrict__ b3, float* __restrict__ out)
{
    __shared__ __align__(16) char smem[65536];

    const int tid = threadIdx.x;
    const int lane = tid & 63, wave = tid >> 6;
    const int l16 = lane & 15, lgr = lane >> 4;
    const short* wt1 = wt;
    const short* wt2 = wt + 65536;
    const short* wt3 = wt + 2 * 65536;

    if (blockIdx.x < SEQ_NBLK) {
        // ================= sequential chains (16 rows) =================
        const int b0 = blockIdx.x * 16;
        char* s_y  = smem;            // [16][256] f32 swizzled, 16KB
        char* s_h1 = smem + 16384;    // [16][256] bf16 swizzled, 8KB
        char* s_h2 = smem + 24576;    // 8KB
        const int cg = wave;

        float bb1[2], bb2[2], bb3[2];
#pragma unroll
        for (int ct = 0; ct < 2; ct++) {
            const int c = cg * 32 + ct * 16 + l16;
            bb1[ct] = b1[c]; bb2[ct] = b2[c]; bb3[ct] = b3[c];
        }
        for (int i = tid; i < 16 * 256 / 4; i += 512) {
            const int r = i >> 6, c = (i & 63) * 4;
            f32x4 v = *(const f32x4*)(lat + (size_t)(b0 + r) * LAT_BSTRIDE + 99 * ND + c);
            *(f32x4*)(s_y + ((r * 1024 + c * 4) ^ ((r & 7) << 5))) = v;
        }
        __syncthreads();

#pragma unroll 1
        for (int step = 0; step < 20; step++) {
            const int k = 100 + step;
            const float dt = ts[k - 1] - ts[k - 2];
            // keep weight loads inside the loop (block LICM->AGPR hoisting)
            const short* w1p = wt1;
            const short* w2p = wt2;
            const short* w3p = wt3;
            asm volatile("" : "+s"(w1p), "+s"(w2p), "+s"(w3p));

            f32x4 acc0, acc1;
            // ---- layer 1: A from s_y (f32), B from L2 ----
            acc0 = (f32x4){0.f, 0.f, 0.f, 0.f};
            acc1 = (f32x4){0.f, 0.f, 0.f, 0.f};
#pragma unroll
            for (int kk = 0; kk < 8; kk++) {
                const int k0 = kk * 32 + lgr * 8;
                const int off = (l16 * 1024 + k0 * 4) ^ ((l16 & 7) << 5);
                f32x4 lo = *(const f32x4*)(s_y + off);
                f32x4 hi = *(const f32x4*)(s_y + off + 16);
                bf16x8 a;
                a[0] = f2bf(lo[0]); a[1] = f2bf(lo[1]); a[2] = f2bf(lo[2]); a[3] = f2bf(lo[3]);
                a[4] = f2bf(hi[0]); a[5] = f2bf(hi[1]); a[6] = f2bf(hi[2]); a[7] = f2bf(hi[3]);
                bf16x8 v0 = *(const bf16x8*)(w1p + (cg * 32 + l16) * 256 + k0);
                bf16x8 v1 = *(const bf16x8*)(w1p + (cg * 32 + 16 + l16) * 256 + k0);
                acc0 = __builtin_amdgcn_mfma_f32_16x16x32_bf16(a, v0, acc0, 0, 0, 0);
                acc1 = __builtin_amdgcn_mfma_f32_16x16x32_bf16(a, v1, acc1, 0, 0, 0);
            }
#pragma unroll
            for (int ct = 0; ct < 2; ct++) {
                const f32x4 av = ct ? acc1 : acc0;
                const int c = cg * 32 + ct * 16 + l16;
#pragma unroll
                for (int j = 0; j < 4; j++) {
                    const int r = lgr * 4 + j;
                    *(short*)(s_h1 + ((r * 512 + c * 2) ^ ((r & 7) << 4))) =
                        f2bf(fast_tanh(av[j] + bb1[ct]));
                }
            }
            __syncthreads();

            // ---- layer 2 ----
            acc0 = (f32x4){0.f, 0.f, 0.f, 0.f};
            acc1 = (f32x4){0.f, 0.f, 0.f, 0.f};
#pragma unroll
            for (int kk = 0; kk < 8; kk++) {
                const int k0 = kk * 32 + lgr * 8;
                bf16x8 a = *(const bf16x8*)(s_h1 + ((l16 * 512 + k0 * 2) ^ ((l16 & 7) << 4)));
                bf16x8 v0 = *(const bf16x8*)(w2p + (cg * 32 + l16) * 256 + k0);
                bf16x8 v1 = *(const bf16x8*)(w2p + (cg * 32 + 16 + l16) * 256 + k0);
                acc0 = __builtin_amdgcn_mfma_f32_16x16x32_bf16(a, v0, acc0, 0, 0, 0);
                acc1 = __builtin_amdgcn_mfma_f32_16x16x32_bf16(a, v1, acc1, 0, 0, 0);
            }
#pragma unroll
            for (int ct = 0; ct < 2; ct++) {
                const f32x4 av = ct ? acc1 : acc0;
                const int c = cg * 32 + ct * 16 + l16;
#pragma unroll
                for (int j = 0; j < 4; j++) {
                    const int r = lgr * 4 + j;
                    *(short*)(s_h2 + ((r * 512 + c * 2) ^ ((r & 7) << 4))) =
                        f2bf(fast_tanh(av[j] + bb2[ct]));
                }
            }
            __syncthreads();

            // ---- layer 3 + Euler update ----
            acc0 = (f32x4){0.f, 0.f, 0.f, 0.f};
            acc1 = (f32x4){0.f, 0.f, 0.f, 0.f};
#pragma unroll
            for (int kk = 0; kk < 8; kk++) {
                const int k0 = kk * 32 + lgr * 8;
                bf16x8 a = *(const bf16x8*)(s_h2 + ((l16 * 512 + k0 * 2) ^ ((l16 & 7) << 4)));
                bf16x8 v0 = *(const bf16x8*)(w3p + (cg * 32 + l16) * 256 + k0);
                bf16x8 v1 = *(const bf16x8*)(w3p + (cg * 32 + 16 + l16) * 256 + k0);
                acc0 = __builtin_amdgcn_mfma_f32_16x16x32_bf16(a, v0, acc0, 0, 0, 0);
                acc1 = __builtin_amdgcn_mfma_f32_16x16x32_bf16(a, v1, acc1, 0, 0, 0);
            }
#pragma unroll
            for (int ct = 0; ct < 2; ct++) {
                const f32x4 av = ct ? acc1 : acc0;
                const int c = cg * 32 + ct * 16 + l16;
                const float bc = ct ? bb3[1] : bb3[0];
#pragma unroll
                for (int j = 0; j < 4; j++) {
                    const int r = lgr * 4 + j;
                    const int yoff = (r * 1024 + c * 4) ^ ((r & 7) << 5);
                    const float yold = *(const float*)(s_y + yoff);
                    const float ynew = yold + (av[j] + bc) * dt;
                    *(float*)(s_y + yoff) = ynew;
                    out[(size_t)(b0 + r) * OUT_BSTRIDE + (size_t)k * ND + c] = ynew;
                }
            }
            __syncthreads();
        }
    } else {
        // ================= parallel f-evals (64 rows) =================
        const int p = blockIdx.x - SEQ_NBLK;
        const int e = p >> 4;                 // 0..97
        const int b0 = (p & 15) * PAR_ROWS;
        const int src_t = (e == 0) ? 0 : (e + 1);
        const int out_k = (e == 0) ? 1 : (e + 2);
        const float dt = (e == 0) ? (ts[1] - ts[0]) : (ts[e + 1] - ts[e]);
        const float* src = lat + (size_t)b0 * LAT_BSTRIDE + (size_t)src_t * ND;

        char* bufA = smem;            // 32KB: A, then h2
        char* bufH = smem + 32768;    // 32KB: h1
        const int cg = wave;

        float bb1[2], bb2[2], bb3[2];
#pragma unroll
        for (int ct = 0; ct < 2; ct++) {
            const int c = cg * 32 + ct * 16 + l16;
            bb1[ct] = b1[c]; bb2[ct] = b2[c]; bb3[ct] = b3[c];
        }

        // stage A = bf16(y), swizzled
        for (int i = tid; i < PAR_ROWS * ND / 4; i += 512) {
            const int r = i >> 6, c = (i & 63) * 4;
            f32x4 v = *(const f32x4*)(src + (size_t)r * LAT_BSTRIDE + c);
            short4v s;
            s[0] = f2bf(v[0]); s[1] = f2bf(v[1]); s[2] = f2bf(v[2]); s[3] = f2bf(v[3]);
            *(short4v*)(bufA + ((r * 512 + c * 2) ^ ((r & 7) << 4))) = s;
        }
        __syncthreads();

        f32x4 acc[4][2];
        par_layer(acc, bufA, wt1, cg, l16, lgr);
        par_store_h(bufH, acc, bb1, cg, l16, lgr);
        __syncthreads();

        par_layer(acc, bufH, wt2, cg, l16, lgr);
        par_store_h(bufA, acc, bb2, cg, l16, lgr);
        __syncthreads();

        par_layer(acc, bufA, wt3, cg, l16, lgr);
#pragma unroll
        for (int rt = 0; rt < 4; rt++)
#pragma unroll
            for (int ct = 0; ct < 2; ct++) {
                const int c = cg * 32 + ct * 16 + l16;
#pragma unroll
                for (int j = 0; j < 4; j++) {
                    const int r = rt * 16 + lgr * 4 + j;
                    const float yold = src[(size_t)r * LAT_BSTRIDE + c];
                    out[(size_t)(b0 + r) * OUT_BSTRIDE + (size_t)out_k * ND + c] =
                        yold + (acc[rt][ct][j] + bb3[ct]) * dt;
                }
            }
    }
}

extern "C" void kernel_launch(void* const* d_in, const int* in_sizes, int n_in,
                              void* d_out, int out_size, void* d_ws, size_t ws_size,
                              hipStream_t stream)
{
    const float* lat = (const float*)d_in[0];
    const float* ts  = (const float*)d_in[1];
    // d_in[2] = time_pred (unused: pred steps are exactly indices 100..119)
    const float* W1  = (const float*)d_in[3];
    const float* b1  = (const float*)d_in[4];
    const float* W2  = (const float*)d_in[5];
    const float* b2  = (const float*)d_in[6];
    const float* W3  = (const float*)d_in[7];
    const float* b3  = (const float*)d_in[8];
    float* out = (float*)d_out;
    short* wt = (short*)d_ws;   // 3 * 256*256 bf16 = 384 KB

    hipLaunchKernelGGL(prep_kernel, dim3(256), dim3(256), 0, stream,
                       W1, W2, W3, lat, wt, out);
    hipLaunchKernelGGL(ode_main, dim3(SEQ_NBLK + PAR_BLKS), dim3(512), 0, stream,
                       lat, ts, wt, b1, b2, b3, out);
}